// Round 1
// 228.964 us; speedup vs baseline: 1.2547x; 1.2547x over previous
//
#include <hip/hip_runtime.h>

// Problem constants
#define LSEQ   16384
#define NB     20
#define NBATCH 128
#define TAPS   513
#define CT     (2*TAPS - 1)   // 1025 combined (autocorrelation) taps
#define MAXSTEP 68            // k-step table entries per band (N+3 <= 68)

// Main-kernel tiling
#define TT     2048           // output times per block
#define SPANE  3088           // staged ext ushorts per batch row (TT + 1024 + 16 prefetch pad)
#define STRIDE 3096           // row stride in ushorts: 16B-aligned, +8 bank stagger (1548 mod 32 = 12)
#define EXTEND 16896          // 512 + LSEQ
#define GMAX   17407          // last valid ext index (LSEQ + 2*512 - 1)

// ws layout (bytes)
#define HDR_OFF  0            // int2 per band {k0, nsteps}: 160 B
#define ATAB_OFF 1024         // bf16 A-fragment table: 20*68*64*16 B = 1.39 MB

typedef short  v8s  __attribute__((ext_vector_type(8)));
typedef __bf16 v8bf __attribute__((ext_vector_type(8)));
typedef float  v16f __attribute__((ext_vector_type(16)));

__device__ __forceinline__ unsigned short f2bf(float f) {  // RNE fp32->bf16
    union { float f; unsigned u; } v; v.f = f;
    return (unsigned short)((v.u + 0x7fffu + ((v.u >> 16) & 1u)) >> 16);
}

__device__ __forceinline__ v16f vzero() {
    v16f z;
    #pragma unroll
    for (int i = 0; i < 16; ++i) z[i] = 0.f;
    return z;
}

// ---- Fused pre-kernel: autocorr -> nonzero range -> A-fragment table ----
// One block per band, 1024 threads (one d per thread -> 4 waves/SIMD so LDS
// latency is TLP-hidden; unroll-4 partial sums break the dependent FMA chain).
__global__ __launch_bounds__(1024) void prep_kernel(
    const float* __restrict__ Kg, int2* __restrict__ hdr, short* __restrict__ atab)
{
    __shared__ float kk[TAPS];
    __shared__ float Cs[CT];
    __shared__ int smin, smax, sk0, sN;
    const int band = blockIdx.x;
    const int tid  = threadIdx.x;

    for (int i = tid; i < TAPS; i += 1024) kk[i] = Kg[band * TAPS + i];
    if (tid == 0) { smin = CT; smax = 0; }
    __syncthreads();

    int lmin = CT, lmax = 0;
    for (int d = tid; d < CT; d += 1024) {
        int al = d - 512; if (al < 0) al = -al;
        const int n = TAPS - al;
        float s0 = 0.f, s1 = 0.f, s2 = 0.f, s3 = 0.f;
        int i = 0;
        for (; i + 3 < n; i += 4) {
            s0 = fmaf(kk[i],     kk[i + al],     s0);
            s1 = fmaf(kk[i + 1], kk[i + 1 + al], s1);
            s2 = fmaf(kk[i + 2], kk[i + 2 + al], s2);
            s3 = fmaf(kk[i + 3], kk[i + 3 + al], s3);
        }
        for (; i < n; ++i) s0 = fmaf(kk[i], kk[i + al], s0);
        float s = (s0 + s1) + (s2 + s3);
        Cs[d] = s;
        if (s != 0.f) { if (d < lmin) lmin = d; if (d > lmax) lmax = d; }
    }
    atomicMin(&smin, lmin);
    atomicMax(&smax, lmax);
    __syncthreads();

    if (tid == 0) {
        int k0 = smin & ~15;
        int k1 = ((smax + 31) >> 4) << 4;
        int N  = (k1 - k0) / 16 + 1;            // <= 65
        int2 h; h.x = k0; h.y = N;
        hdr[band] = h;
        sk0 = k0; sN = N;
    }
    __syncthreads();

    const int k0 = sk0, N = sN;
    // Fill N+3 rows: main kernel prefetches A at depth 3 (reads row s+3 <= N+2).
    for (int idx = tid; idx < (N + 3) * 64; idx += 1024) {
        int s = idx >> 6, lane = idx & 63;
        int m = lane & 31, kh = lane >> 5;
        int base = k0 + 16 * s + 8 * kh - m;
        v8s r;
        #pragma unroll
        for (int j = 0; j < 8; ++j) {
            int ci = base + j;
            float v = (ci >= 0 && ci < CT) ? Cs[ci] : 0.f;
            r[j] = (short)f2bf(v);
        }
        *(v8s*)(atab + ((size_t)(band * MAXSTEP + s) * 64 + lane) * 8) = r;
    }
}

// ---- Main kernel: stage ext once, sweep a band group, MFMA 32x32x16 ----
// Block: 8 batches x 2048 times, 4 waves (wave w: times [512w, 512w+512)).
// Wave tile: m = fine time (32), n = brow + 8*tb (8 batches x 4 time-subtiles
// of 32); 4 accumulators at time offsets 0/128/256/384 -> 4 MFMAs share one
// A-fragment load and one loop iteration (2x overhead amortization vs 2-acc).
__global__ __launch_bounds__(256, 3) void filt_main(
    const float* __restrict__ x, const short* __restrict__ atab,
    const int2* __restrict__ hdr, float* __restrict__ out)
{
    __shared__ __align__(16) unsigned short extl[8 * STRIDE];
    const int tid = threadIdx.x;
    const int tile = blockIdx.x, grp = blockIdx.y, bg = blockIdx.z;
    const int T0 = tile * TT;

    // ---- Stage odd-extended x as bf16 (8 batch rows, SPANE each) ----
    const bool edge = (T0 < 512) || (T0 + SPANE > EXTEND);
    for (int b = 0; b < 8; ++b) {
        const float* xb = x + (size_t)(bg * 8 + b) * LSEQ;
        float x0 = 0.f, xN = 0.f;
        if (edge) { x0 = xb[0]; xN = xb[LSEQ - 1]; }
        for (int e4 = tid; e4 < SPANE / 4; e4 += 256) {
            const int e = 4 * e4;
            const int g0 = T0 + e;
            float v0, v1, v2, v3;
            if (g0 >= 512 && g0 + 4 <= EXTEND) {
                float4 xv = *(const float4*)(xb + (g0 - 512));
                v0 = xv.x; v1 = xv.y; v2 = xv.z; v3 = xv.w;
            } else {
                float vv[4];
                #pragma unroll
                for (int t = 0; t < 4; ++t) {
                    int g = g0 + t; if (g > GMAX) g = GMAX;  // prefetch pad, never read
                    vv[t] = (g < 512)    ? 2.f * x0 - xb[512 - g]
                          : (g < EXTEND) ? xb[g - 512]
                          :                2.f * xN - xb[2 * LSEQ + 512 - 2 - g];
                }
                v0 = vv[0]; v1 = vv[1]; v2 = vv[2]; v3 = vv[3];
            }
            ushort4 q = make_ushort4(f2bf(v0), f2bf(v1), f2bf(v2), f2bf(v3));
            *(ushort4*)&extl[b * STRIDE + e] = q;
        }
    }
    __syncthreads();

    const int lane = tid & 63;
    const int w    = tid >> 6;
    const int n    = lane & 31, kh = lane >> 5;
    const int brow = n & 7,  tb = n >> 3;
    const unsigned short* bpb = extl + brow * STRIDE + 512 * w + 32 * tb + 8 * kh;

    // Load-balanced band groups (sum of k-steps ~62-80 per group)
    const int g_start[6] = {0, 4, 8, 11, 15, 20};
    const int g_list[20] = {0,19,18,17, 1,16,15,14, 2,3,13, 4,5,6,12, 7,8,9,10,11};

    for (int bi = g_start[grp]; bi < g_start[grp + 1]; ++bi) {
        const int band = g_list[bi];
        const int2 hh = hdr[band];
        const int k0 = hh.x, N = hh.y;
        const unsigned short* bp = bpb + k0;
        const short* ap = atab + (size_t)(band * MAXSTEP) * 512 + lane * 8;

        v16f ac0 = vzero(), ac1 = vzero(), ac2 = vzero(), ac3 = vzero();
        // A prefetch depth 3 (covers ~3 iterations of L2 latency)
        v8bf A0 = __builtin_bit_cast(v8bf, *(const v8s*)ap);
        v8bf A1 = __builtin_bit_cast(v8bf, *(const v8s*)(ap + 512));
        v8bf A2 = __builtin_bit_cast(v8bf, *(const v8s*)(ap + 1024));
        v8bf B0 = *(const v8bf*)(bp);
        v8bf B1 = *(const v8bf*)(bp + 128);
        v8bf B2 = *(const v8bf*)(bp + 256);
        v8bf B3 = *(const v8bf*)(bp + 384);

        for (int s = 0; s < N; ++s) {
            v8bf An  = __builtin_bit_cast(v8bf, *(const v8s*)(ap + (size_t)(s + 3) * 512));
            const unsigned short* bn = bp + 16 * (s + 1);
            v8bf Bn0 = *(const v8bf*)(bn);
            v8bf Bn1 = *(const v8bf*)(bn + 128);
            v8bf Bn2 = *(const v8bf*)(bn + 256);
            v8bf Bn3 = *(const v8bf*)(bn + 384);
            ac0 = __builtin_amdgcn_mfma_f32_32x32x16_bf16(A0, B0, ac0, 0, 0, 0);
            ac1 = __builtin_amdgcn_mfma_f32_32x32x16_bf16(A0, B1, ac1, 0, 0, 0);
            ac2 = __builtin_amdgcn_mfma_f32_32x32x16_bf16(A0, B2, ac2, 0, 0, 0);
            ac3 = __builtin_amdgcn_mfma_f32_32x32x16_bf16(A0, B3, ac3, 0, 0, 0);
            A0 = A1; A1 = A2; A2 = An;
            B0 = Bn0; B1 = Bn1; B2 = Bn2; B3 = Bn3;
        }

        // Epilogue: D row = (reg&3) + 8*(reg>>2) + 4*kh  (m = fine time)
        float* ob = out + ((size_t)(bg * 8 + brow) * NB + band) * LSEQ
                        + T0 + 512 * w + 32 * tb + 4 * kh;
        #pragma unroll
        for (int q = 0; q < 4; ++q) {
            *(float4*)(ob +       8 * q) = make_float4(ac0[4*q], ac0[4*q+1], ac0[4*q+2], ac0[4*q+3]);
            *(float4*)(ob + 128 + 8 * q) = make_float4(ac1[4*q], ac1[4*q+1], ac1[4*q+2], ac1[4*q+3]);
            *(float4*)(ob + 256 + 8 * q) = make_float4(ac2[4*q], ac2[4*q+1], ac2[4*q+2], ac2[4*q+3]);
            *(float4*)(ob + 384 + 8 * q) = make_float4(ac3[4*q], ac3[4*q+1], ac3[4*q+2], ac3[4*q+3]);
        }
    }
}

extern "C" void kernel_launch(void* const* d_in, const int* in_sizes, int n_in,
                              void* d_out, int out_size, void* d_ws, size_t ws_size,
                              hipStream_t stream) {
    const float* x  = (const float*)d_in[0];  // (128, 1, 16384) fp32
    const float* Kg = (const float*)d_in[1];  // (20, 513) fp32
    float* out = (float*)d_out;               // (128, 1, 20, 16384) fp32

    char* wsb = (char*)d_ws;
    int2*  hdr  = (int2*)(wsb + HDR_OFF);
    short* atab = (short*)(wsb + ATAB_OFF);

    prep_kernel<<<dim3(NB), dim3(1024), 0, stream>>>(Kg, hdr, atab);
    filt_main<<<dim3(LSEQ / TT, 5, NBATCH / 8), dim3(256), 0, stream>>>(x, atab, hdr, out);
}

// Round 2
// 223.126 us; speedup vs baseline: 1.2875x; 1.0262x over previous
//
#include <hip/hip_runtime.h>

// Problem constants
#define LSEQ   16384
#define NB     20
#define NBATCH 128
#define TAPS   513
#define CT     (2*TAPS - 1)   // 1025 combined (autocorrelation) taps
#define MAXSTEP 72            // k-step table rows per band (N+3 <= 69 fits; no cross-band alias)

// Main-kernel tiling
#define TT     2048           // output times per block
#define SPANE  3088           // staged ext ushorts per batch row (TT + 1024 + 16 prefetch pad)
#define STRIDE 3096           // row stride in ushorts: 16B-aligned, +8 bank stagger
#define EXTEND 16896          // 512 + LSEQ
#define GMAX   17407          // last valid ext index (LSEQ + 2*512 - 1)

// ws layout (bytes)
#define HDR_OFF  0            // int2 per band {k0, nsteps}: 160 B
#define MMX_OFF  256          // int2 per (band, chunk) {min,max}: 20*9*8 = 1440 B
#define CS_OFF   4096         // fp32 autocorr: 20 * CSTRIDE floats = 83.2 KB
#define CSTRIDE  1040         // floats per band row (1025 padded)
#define ATAB_OFF 98304        // bf16 A-fragment table: 20*72*64*16 B = 1.47 MB

typedef short  v8s  __attribute__((ext_vector_type(8)));
typedef __bf16 v8bf __attribute__((ext_vector_type(8)));
typedef float  v16f __attribute__((ext_vector_type(16)));

__device__ __forceinline__ unsigned short f2bf(float f) {  // RNE fp32->bf16
    union { float f; unsigned u; } v; v.f = f;
    return (unsigned short)((v.u + 0x7fffu + ((v.u >> 16) & 1u)) >> 16);
}

__device__ __forceinline__ v16f vzero() {
    v16f z;
    #pragma unroll
    for (int i = 0; i < 16; ++i) z[i] = 0.f;
    return z;
}

// ---- Autocorr kernel: grid (20 bands, 9 chunks of 128 d) x 512 threads ----
// Thread (rel, q): d = 128*chunk + rel, computes quarter q of the i-range.
// Quarter starts forced to multiples of 4 so kk[i..i+3] vectorizes (16B LDS).
__global__ __launch_bounds__(512) void autoc_kernel(
    const float* __restrict__ Kg, float* __restrict__ Cs, int2* __restrict__ mmx)
{
    __shared__ __align__(16) float kk[TAPS];
    __shared__ float ps[512];
    __shared__ int smin, smax;
    const int band = blockIdx.x, y = blockIdx.y;
    const int tid = threadIdx.x;
    const int rel = tid & 127, q = tid >> 7;
    const int d = 128 * y + rel;

    for (int i = tid; i < TAPS; i += 512) kk[i] = Kg[band * TAPS + i];
    if (tid == 0) { smin = CT; smax = 0; }
    __syncthreads();

    float s = 0.f;
    if (d < CT) {
        int al = d - 512; if (al < 0) al = -al;
        const int n = TAPS - al;
        const int nq = (((n + 3) >> 2) + 3) & ~3;   // quarter size, multiple of 4
        int i0 = q * nq, i1 = i0 + nq; if (i1 > n) i1 = n;
        float s0 = 0.f, s1 = 0.f, s2 = 0.f, s3 = 0.f;
        int i = i0;
        for (; i + 3 < i1; i += 4) {
            s0 = fmaf(kk[i],     kk[i + al],     s0);
            s1 = fmaf(kk[i + 1], kk[i + 1 + al], s1);
            s2 = fmaf(kk[i + 2], kk[i + 2 + al], s2);
            s3 = fmaf(kk[i + 3], kk[i + 3 + al], s3);
        }
        for (; i < i1; ++i) s0 = fmaf(kk[i], kk[i + al], s0);
        s = (s0 + s1) + (s2 + s3);
    }
    ps[tid] = s;
    __syncthreads();
    if (q == 0 && d < CT) {
        float tot = (ps[rel] + ps[rel + 128]) + (ps[rel + 256] + ps[rel + 384]);
        Cs[band * CSTRIDE + d] = tot;
        if (tot != 0.f) { atomicMin(&smin, d); atomicMax(&smax, d); }
    }
    __syncthreads();
    if (tid == 0) { int2 r; r.x = smin; r.y = smax; mmx[band * 9 + y] = r; }
}

// ---- Table kernel: one block per band, reduce ranges, emit A-fragments ----
__global__ __launch_bounds__(1024) void table_kernel(
    const float* __restrict__ Cs, const int2* __restrict__ mmx,
    int2* __restrict__ hdr, short* __restrict__ atab)
{
    __shared__ int sk0, sN;
    const int band = blockIdx.x, tid = threadIdx.x;
    if (tid == 0) {
        int mn = CT, mx = 0;
        for (int j = 0; j < 9; ++j) {
            int2 r = mmx[band * 9 + j];
            if (r.x < mn) mn = r.x;
            if (r.y > mx) mx = r.y;
        }
        int k0 = mn & ~15;
        int k1 = ((mx + 31) >> 4) << 4;
        int N  = (k1 - k0) / 16 + 1;            // <= 66
        int2 h; h.x = k0; h.y = N;
        hdr[band] = h;
        sk0 = k0; sN = N;
    }
    __syncthreads();
    const int k0 = sk0, N = sN;
    int nf = N + 3; if (nf > MAXSTEP) nf = MAXSTEP;  // never alias next band
    const float* cb = Cs + band * CSTRIDE;
    for (int idx = tid; idx < nf * 64; idx += 1024) {
        int s = idx >> 6, lane = idx & 63;
        int m = lane & 31, kh = lane >> 5;
        int base = k0 + 16 * s + 8 * kh - m;
        v8s r;
        #pragma unroll
        for (int j = 0; j < 8; ++j) {
            int ci = base + j;
            float v = (ci >= 0 && ci < CT) ? cb[ci] : 0.f;
            r[j] = (short)f2bf(v);
        }
        *(v8s*)(atab + ((size_t)(band * MAXSTEP + s) * 64 + lane) * 8) = r;
    }
}

// ---- Main kernel: stage ext once, sweep a band group, MFMA 32x32x16 ----
// Block: 8 batches x 2048 times, 4 waves (wave w: times [512w, 512w+512)).
// Wave tile: m = fine time (32), n = brow + 8*tb (8 batches x 4 time-subtiles
// of 32); 4 accumulators at time offsets 0/128/256/384 share one A-load.
__global__ __launch_bounds__(256, 3) void filt_main(
    const float* __restrict__ x, const short* __restrict__ atab,
    const int2* __restrict__ hdr, float* __restrict__ out)
{
    __shared__ __align__(16) unsigned short extl[8 * STRIDE];
    const int tid = threadIdx.x;
    const int tile = blockIdx.x, grp = blockIdx.y, bg = blockIdx.z;
    const int T0 = tile * TT;

    // ---- Stage odd-extended x as bf16 (8 batch rows, SPANE each) ----
    const bool edge = (T0 < 512) || (T0 + SPANE > EXTEND);
    for (int b = 0; b < 8; ++b) {
        const float* xb = x + (size_t)(bg * 8 + b) * LSEQ;
        float x0 = 0.f, xN = 0.f;
        if (edge) { x0 = xb[0]; xN = xb[LSEQ - 1]; }
        for (int e4 = tid; e4 < SPANE / 4; e4 += 256) {
            const int e = 4 * e4;
            const int g0 = T0 + e;
            float v0, v1, v2, v3;
            if (g0 >= 512 && g0 + 4 <= EXTEND) {
                float4 xv = *(const float4*)(xb + (g0 - 512));
                v0 = xv.x; v1 = xv.y; v2 = xv.z; v3 = xv.w;
            } else {
                float vv[4];
                #pragma unroll
                for (int t = 0; t < 4; ++t) {
                    int g = g0 + t; if (g > GMAX) g = GMAX;  // prefetch pad, never read
                    vv[t] = (g < 512)    ? 2.f * x0 - xb[512 - g]
                          : (g < EXTEND) ? xb[g - 512]
                          :                2.f * xN - xb[2 * LSEQ + 512 - 2 - g];
                }
                v0 = vv[0]; v1 = vv[1]; v2 = vv[2]; v3 = vv[3];
            }
            ushort4 qv = make_ushort4(f2bf(v0), f2bf(v1), f2bf(v2), f2bf(v3));
            *(ushort4*)&extl[b * STRIDE + e] = qv;
        }
    }
    __syncthreads();

    const int lane = tid & 63;
    const int w    = tid >> 6;
    const int n    = lane & 31, kh = lane >> 5;
    const int brow = n & 7,  tb = n >> 3;
    const unsigned short* bpb = extl + brow * STRIDE + 512 * w + 32 * tb + 8 * kh;

    // Load-balanced band groups (sum of k-steps ~63-82 per group)
    const int g_start[6] = {0, 4, 8, 11, 15, 20};
    const int g_list[20] = {0,19,18,17, 1,16,15,14, 2,3,13, 4,5,6,12, 7,8,9,10,11};

    for (int bi = g_start[grp]; bi < g_start[grp + 1]; ++bi) {
        const int band = g_list[bi];
        const int2 hh = hdr[band];
        const int k0 = hh.x, N = hh.y;
        const unsigned short* bp = bpb + k0;
        const short* ap = atab + (size_t)(band * MAXSTEP) * 512 + lane * 8;

        v16f ac0 = vzero(), ac1 = vzero(), ac2 = vzero(), ac3 = vzero();
        // A prefetch depth 3 (covers ~3 iterations of L2 latency)
        v8bf A0 = __builtin_bit_cast(v8bf, *(const v8s*)ap);
        v8bf A1 = __builtin_bit_cast(v8bf, *(const v8s*)(ap + 512));
        v8bf A2 = __builtin_bit_cast(v8bf, *(const v8s*)(ap + 1024));
        v8bf B0 = *(const v8bf*)(bp);
        v8bf B1 = *(const v8bf*)(bp + 128);
        v8bf B2 = *(const v8bf*)(bp + 256);
        v8bf B3 = *(const v8bf*)(bp + 384);

        #pragma unroll 2
        for (int s = 0; s < N; ++s) {
            v8bf An  = __builtin_bit_cast(v8bf, *(const v8s*)(ap + (size_t)(s + 3) * 512));
            const unsigned short* bn = bp + 16 * (s + 1);
            v8bf Bn0 = *(const v8bf*)(bn);
            v8bf Bn1 = *(const v8bf*)(bn + 128);
            v8bf Bn2 = *(const v8bf*)(bn + 256);
            v8bf Bn3 = *(const v8bf*)(bn + 384);
            __builtin_amdgcn_s_setprio(1);
            ac0 = __builtin_amdgcn_mfma_f32_32x32x16_bf16(A0, B0, ac0, 0, 0, 0);
            ac1 = __builtin_amdgcn_mfma_f32_32x32x16_bf16(A0, B1, ac1, 0, 0, 0);
            ac2 = __builtin_amdgcn_mfma_f32_32x32x16_bf16(A0, B2, ac2, 0, 0, 0);
            ac3 = __builtin_amdgcn_mfma_f32_32x32x16_bf16(A0, B3, ac3, 0, 0, 0);
            __builtin_amdgcn_s_setprio(0);
            A0 = A1; A1 = A2; A2 = An;
            B0 = Bn0; B1 = Bn1; B2 = Bn2; B3 = Bn3;
        }

        // Epilogue: D row = (reg&3) + 8*(reg>>2) + 4*kh  (m = fine time)
        float* ob = out + ((size_t)(bg * 8 + brow) * NB + band) * LSEQ
                        + T0 + 512 * w + 32 * tb + 4 * kh;
        #pragma unroll
        for (int q = 0; q < 4; ++q) {
            *(float4*)(ob +       8 * q) = make_float4(ac0[4*q], ac0[4*q+1], ac0[4*q+2], ac0[4*q+3]);
            *(float4*)(ob + 128 + 8 * q) = make_float4(ac1[4*q], ac1[4*q+1], ac1[4*q+2], ac1[4*q+3]);
            *(float4*)(ob + 256 + 8 * q) = make_float4(ac2[4*q], ac2[4*q+1], ac2[4*q+2], ac2[4*q+3]);
            *(float4*)(ob + 384 + 8 * q) = make_float4(ac3[4*q], ac3[4*q+1], ac3[4*q+2], ac3[4*q+3]);
        }
    }
}

extern "C" void kernel_launch(void* const* d_in, const int* in_sizes, int n_in,
                              void* d_out, int out_size, void* d_ws, size_t ws_size,
                              hipStream_t stream) {
    const float* x  = (const float*)d_in[0];  // (128, 1, 16384) fp32
    const float* Kg = (const float*)d_in[1];  // (20, 513) fp32
    float* out = (float*)d_out;               // (128, 1, 20, 16384) fp32

    char* wsb = (char*)d_ws;
    int2*  hdr  = (int2*)(wsb + HDR_OFF);
    int2*  mmx  = (int2*)(wsb + MMX_OFF);
    float* Cs   = (float*)(wsb + CS_OFF);
    short* atab = (short*)(wsb + ATAB_OFF);

    autoc_kernel<<<dim3(NB, 9), dim3(512), 0, stream>>>(Kg, Cs, mmx);
    table_kernel<<<dim3(NB), dim3(1024), 0, stream>>>(Cs, mmx, hdr, atab);
    filt_main<<<dim3(LSEQ / TT, 5, NBATCH / 8), dim3(256), 0, stream>>>(x, atab, hdr, out);
}